// Round 9
// baseline (554.868 us; speedup 1.0000x reference)
//
#include <hip/hip_runtime.h>
#include <stdint.h>

#define L_SEQ 512
#define BATCH 64
#define KTOT  512   // E + H
#define TDIM  50
#define HID2  512   // 2*H
#define ROWSTRIDE ((long)BATCH * HID2)  // floats per l-slice of hidden
#define NLOG2E 1.4426950408889634f     // P' = -log2e*(Wx+b); W' = -log2e*W_h

typedef __attribute__((ext_vector_type(8))) short bf16x8;
typedef __attribute__((ext_vector_type(4))) float f32x4;

static __device__ __forceinline__ unsigned short f2bf(float f) {
  union { float f; unsigned int u; } v; v.f = f;
  unsigned int r = (v.u + 0x7FFFu + ((v.u >> 16) & 1u)) >> 16;  // RNE
  return (unsigned short)r;
}

static __device__ __forceinline__ bf16x8 pack8(const float* f) {
  bf16x8 r;
#pragma unroll
  for (int i = 0; i < 8; ++i) r[i] = (short)f2bf(f[i]);
  return r;
}

// HW packed f32->bf16 (RNE): lo16 = bf16(a), hi16 = bf16(b)
static __device__ __forceinline__ unsigned cvt_pk_bf16(float a, float b) {
  unsigned r;
  asm("v_cvt_pk_bf16_f32 %0, %1, %2" : "=v"(r) : "v"(a), "v"(b));
  return r;
}

// ---------------------------------------------------------------------------
// pre_kernel: P'[g][dir*256 + j] = -log2e * (emb[text] . W_dir[j][0:256] + b)
// written INTO the hidden output region (scan RMWs it in place).
// dir=1 rows are time-reversed (row l holds x[511-l] terms).
// ---------------------------------------------------------------------------
__global__ __launch_bounds__(512) void pre_kernel(
    const int* __restrict__ text, const float* __restrict__ emb,
    const float* __restrict__ W_f, const float* __restrict__ b_f,
    const float* __restrict__ W_b, const float* __restrict__ b_b,
    float* __restrict__ hidden) {
  const int blk = blockIdx.x;          // 0..511
  const int dir = blk >> 8;
  const int base = (blk & 255) * 128;  // g-row base (g = l*64 + b)
  const float* W    = dir ? W_b : W_f;
  const float* bias = dir ? b_b : b_f;
  const int tid = threadIdx.x;
  const int w = tid >> 6, ln = tid & 63, m16 = ln & 15, g4 = ln >> 4;

  __shared__ __align__(16) unsigned char xLds[16 * 512];

  // W x-part fragments: wave w owns j-range [w*32, w*32+32), K=256
  bf16x8 wfrag[2][8];
#pragma unroll
  for (int t = 0; t < 2; ++t) {
    const int j0 = w * 32 + t * 16 + m16;
#pragma unroll
    for (int kk = 0; kk < 8; ++kk) {
      const float* p = W + (long)j0 * KTOT + kk * 32 + g4 * 8;
      float4 p0 = *(const float4*)(p);
      float4 p1 = *(const float4*)(p + 4);
      float f[8] = {p0.x, p0.y, p0.z, p0.w, p1.x, p1.y, p1.z, p1.w};
      wfrag[t][kk] = pack8(f);
    }
  }
  float biasr[2][4];
#pragma unroll
  for (int t = 0; t < 2; ++t)
#pragma unroll
    for (int r = 0; r < 4; ++r) biasr[t][r] = bias[w * 32 + t * 16 + 4 * g4 + r];

  const int xm = tid >> 5;          // staged row
  const int e0 = (tid & 31) * 8;    // 8 contiguous f32 per thread

  for (int mt = 0; mt < 8; ++mt) {
    const int g = base + mt * 16 + xm;
    const int l = g >> 6, b = g & 63;
    const int srcl = dir ? (L_SEQ - 1 - l) : l;
    const int tok = text[srcl * BATCH + b];
    const float* xp = emb + (long)tok * 256 + e0;
    float4 a0 = *(const float4*)(xp);
    float4 a1 = *(const float4*)(xp + 4);
    float f[8] = {a0.x, a0.y, a0.z, a0.w, a1.x, a1.y, a1.z, a1.w};
    bf16x8 xv = pack8(f);
    if (mt) __syncthreads();  // prior tile's reads done before overwrite
    *(bf16x8*)(xLds + xm * 512 + ((e0 * 2) ^ ((xm & 7) << 4))) = xv;
    __syncthreads();

    f32x4 acc0 = {0.f, 0.f, 0.f, 0.f};
    f32x4 acc1 = {0.f, 0.f, 0.f, 0.f};
#pragma unroll
    for (int kk = 0; kk < 8; ++kk) {
      bf16x8 uf = *(const bf16x8*)(xLds + m16 * 512 +
                                   (((kk * 64) + g4 * 16) ^ ((m16 & 7) << 4)));
      acc0 = __builtin_amdgcn_mfma_f32_16x16x32_bf16(wfrag[0][kk], uf, acc0, 0, 0, 0);
      acc1 = __builtin_amdgcn_mfma_f32_16x16x32_bf16(wfrag[1][kk], uf, acc1, 0, 0, 0);
    }
    const int gg = base + mt * 16 + m16;
    float* op = hidden + (long)gg * HID2 + dir * 256 + w * 32 + 4 * g4;
    *(float4*)(op)      = make_float4(-NLOG2E * (acc0[0] + biasr[0][0]),
                                      -NLOG2E * (acc0[1] + biasr[0][1]),
                                      -NLOG2E * (acc0[2] + biasr[0][2]),
                                      -NLOG2E * (acc0[3] + biasr[0][3]));
    *(float4*)(op + 16) = make_float4(-NLOG2E * (acc1[0] + biasr[1][0]),
                                      -NLOG2E * (acc1[1] + biasr[1][1]),
                                      -NLOG2E * (acc1[2] + biasr[1][2]),
                                      -NLOG2E * (acc1[3] + biasr[1][3]));
  }
}

// ---------------------------------------------------------------------------
// scan_kernel: h' = 1/(1+exp2(P' + W'.h)), 8 WGs, 256 threads = 4 waves
// (1/SIMD), 4 j-tiles (64 j) per wave, K=256.
// r9: halve the LDS read pipe (32 ds_read_b128/CU/step) and run the sigma
// tail contention-free (1 wave/SIMD). Fragment-linear LDS layout:
//   read  uf[kk] at kk*1024 + ln*16                       (1KB/instr)
//   write h'(t)  at (w*2+(t>>1))*1024 + ((t&1)*2+(g4>>1))*256
//                  + m16*16 + (g4&1)*8                    (512B/instr)
// P' prefetched 2 steps ahead (refill issued last), lgkmcnt-only barrier.
// ---------------------------------------------------------------------------
__global__ __launch_bounds__(256, 1) void scan_kernel(
    const float* __restrict__ W_f, const float* __restrict__ W_b,
    float* __restrict__ hidden) {
  const int wg  = blockIdx.x;     // 0..7
  const int dir = wg >> 2;
  const int b0  = (wg & 3) * 16;
  const int tid = threadIdx.x;
  const int w = tid >> 6, ln = tid & 63, m16 = ln & 15, g4 = ln >> 4;
  const float* W = dir ? W_b : W_f;

  __shared__ __align__(16) unsigned char hLds[2][8 * 1024];

  // W h-part fragments (pre-scaled by -log2e): wave w owns j in [w*64, w*64+64)
  bf16x8 wfrag[4][8];
#pragma unroll
  for (int t = 0; t < 4; ++t) {
    const int j0 = w * 64 + t * 16 + m16;
#pragma unroll
    for (int kk = 0; kk < 8; ++kk) {
      const float* p = W + (long)j0 * KTOT + 256 + kk * 32 + g4 * 8;
      float4 p0 = *(const float4*)(p);
      float4 p1 = *(const float4*)(p + 4);
      float f[8] = {-NLOG2E * p0.x, -NLOG2E * p0.y, -NLOG2E * p0.z, -NLOG2E * p0.w,
                    -NLOG2E * p1.x, -NLOG2E * p1.y, -NLOG2E * p1.z, -NLOG2E * p1.w};
      wfrag[t][kk] = pack8(f);
    }
  }

  // fragment-linear LDS offsets
  int rdoff[8];
#pragma unroll
  for (int kk = 0; kk < 8; ++kk) rdoff[kk] = kk * 1024 + ln * 16;
  int wroff[4];
#pragma unroll
  for (int t = 0; t < 4; ++t)
    wroff[t] = (w * 2 + (t >> 1)) * 1024 + ((t & 1) * 2 + (g4 >> 1)) * 256 +
               m16 * 16 + (g4 & 1) * 8;

  // zero h buffer 0 (256 threads x 32 B = 8 KB)
  *(f32x4*)(&hLds[0][0] + tid * 32) = f32x4{0.f, 0.f, 0.f, 0.f};
  *(f32x4*)(&hLds[0][0] + tid * 32 + 16) = f32x4{0.f, 0.f, 0.f, 0.f};

  // per-lane column offset into a hidden l-slice (P' read & h write alias)
  const long roff = (long)(b0 + m16) * HID2 + dir * 256 + w * 64 + 4 * g4;

  // P' register sets: A = even steps, B = odd steps
  f32x4 pA[4], pB[4];
#pragma unroll
  for (int t = 0; t < 4; ++t) {
    pA[t] = *(const f32x4*)(hidden + roff + t * 16);
    pB[t] = *(const f32x4*)(hidden + ROWSTRIDE + roff + t * 16);
  }

  __syncthreads();

// one scan step: h from hLds[BUF] -> h' into hLds[BUF^1]; store row SROW;
// refill PF[] with P'[SROW+2] at the very end (clamped at tail).
#define STEP(BUF, PF, SROW)                                                    \
  {                                                                            \
    bf16x8 uf[8];                                                              \
    _Pragma("unroll")                                                          \
    for (int kk = 0; kk < 8; ++kk)                                             \
      uf[kk] = *(const bf16x8*)(&hLds[BUF][0] + rdoff[kk]);                    \
    f32x4 acc[4];                                                              \
    _Pragma("unroll")                                                          \
    for (int t = 0; t < 4; ++t) acc[t] = f32x4{0.f, 0.f, 0.f, 0.f};            \
    _Pragma("unroll")                                                          \
    for (int kk = 0; kk < 8; ++kk)                                             \
      _Pragma("unroll")                                                        \
      for (int t = 0; t < 4; ++t)                                              \
        acc[t] = __builtin_amdgcn_mfma_f32_16x16x32_bf16(wfrag[t][kk], uf[kk], \
                                                         acc[t], 0, 0, 0);     \
    float* gp = hidden + (long)(SROW)*ROWSTRIDE + roff;                        \
    _Pragma("unroll")                                                          \
    for (int t = 0; t < 4; ++t) {                                              \
      float h[4];                                                              \
      _Pragma("unroll")                                                        \
      for (int r = 0; r < 4; ++r)                                              \
        h[r] = __builtin_amdgcn_rcpf(                                          \
            1.f + __builtin_amdgcn_exp2f(acc[t][r] + PF[t][r]));               \
      *(uint2*)(&hLds[(BUF) ^ 1][0] + wroff[t]) =                              \
          make_uint2(cvt_pk_bf16(h[0], h[1]), cvt_pk_bf16(h[2], h[3]));        \
      *(float4*)(gp + t * 16) = make_float4(h[0], h[1], h[2], h[3]);           \
    }                                                                          \
    {                                                                          \
      const long rn = ((SROW) + 2 < L_SEQ) ? (SROW) + 2 : L_SEQ - 1;           \
      const float* lp = hidden + rn * ROWSTRIDE + roff;                        \
      _Pragma("unroll")                                                        \
      for (int t = 0; t < 4; ++t) PF[t] = *(const f32x4*)(lp + t * 16);        \
    }                                                                          \
    asm volatile("s_waitcnt lgkmcnt(0)" ::: "memory");                         \
    __builtin_amdgcn_s_barrier();                                              \
    asm volatile("" ::: "memory");                                             \
  }

  for (int s = 0; s < L_SEQ; s += 2) {
    STEP(0, pA, s)
    STEP(1, pB, s + 1)
  }
#undef STEP
}

// ---------------------------------------------------------------------------
// out[lb][t] = hidden[lb][:] . W_out[t][:] + b_out[t]
// ---------------------------------------------------------------------------
__global__ __launch_bounds__(64) void out_kernel(
    const float* __restrict__ hidden, const float* __restrict__ W_out,
    const float* __restrict__ b_out, float* __restrict__ out) {
  const int m0 = blockIdx.x * 16;
  const int ln = threadIdx.x;
  const int m16 = ln & 15, g4 = ln >> 4;

  bf16x8 a[16];
  const float* hp = hidden + (long)(m0 + m16) * HID2 + g4 * 8;
#pragma unroll
  for (int kk = 0; kk < 16; ++kk) {
    float4 p0 = *(const float4*)(hp + kk * 32);
    float4 p1 = *(const float4*)(hp + kk * 32 + 4);
    float f[8] = {p0.x, p0.y, p0.z, p0.w, p1.x, p1.y, p1.z, p1.w};
    a[kk] = pack8(f);
  }
#pragma unroll
  for (int nt = 0; nt < 4; ++nt) {
    const int trow = nt * 16 + m16;
    const bool valid = trow < TDIM;
    f32x4 acc = {0.f, 0.f, 0.f, 0.f};
    const float* wp = W_out + (long)trow * HID2 + g4 * 8;
#pragma unroll
    for (int kk = 0; kk < 16; ++kk) {
      bf16x8 bf;
      if (valid) {
        float4 p0 = *(const float4*)(wp + kk * 32);
        float4 p1 = *(const float4*)(wp + kk * 32 + 4);
        float f[8] = {p0.x, p0.y, p0.z, p0.w, p1.x, p1.y, p1.z, p1.w};
        bf = pack8(f);
      } else {
#pragma unroll
        for (int i = 0; i < 8; ++i) bf[i] = 0;
      }
      acc = __builtin_amdgcn_mfma_f32_16x16x32_bf16(a[kk], bf, acc, 0, 0, 0);
    }
    if (valid) {
      float bo = b_out[trow];
#pragma unroll
      for (int r = 0; r < 4; ++r)
        out[(long)(m0 + 4 * g4 + r) * TDIM + trow] = acc[r] + bo;
    }
  }
}

extern "C" void kernel_launch(void* const* d_in, const int* in_sizes, int n_in,
                              void* d_out, int out_size, void* d_ws, size_t ws_size,
                              hipStream_t stream) {
  const int*   text  = (const int*)d_in[0];
  const float* emb   = (const float*)d_in[1];
  const float* W_f   = (const float*)d_in[2];
  const float* b_f   = (const float*)d_in[3];
  const float* W_b   = (const float*)d_in[4];
  const float* b_b   = (const float*)d_in[5];
  const float* W_out = (const float*)d_in[6];
  const float* b_out = (const float*)d_in[7];
  float* out    = (float*)d_out;
  float* hidden = out + (long)L_SEQ * BATCH * TDIM;  // second tuple output

  pre_kernel<<<512, 512, 0, stream>>>(text, emb, W_f, b_f, W_b, b_b, hidden);
  scan_kernel<<<8, 256, 0, stream>>>(W_f, W_b, hidden);
  out_kernel<<<2048, 64, 0, stream>>>(hidden, W_out, b_out, out);
}

// Round 11
// 430.272 us; speedup vs baseline: 1.2896x; 1.2896x over previous
//
#include <hip/hip_runtime.h>
#include <stdint.h>

#define L_SEQ 512
#define BATCH 64
#define KTOT  512   // E + H
#define TDIM  50
#define HID2  512   // 2*H
#define ROWSTRIDE ((long)BATCH * HID2)  // floats per l-slice of hidden
#define NLOG2E 1.4426950408889634f     // P' = -log2e*(Wx+b); W' = -log2e*W_h

typedef __attribute__((ext_vector_type(8))) short bf16x8;
typedef __attribute__((ext_vector_type(4))) float f32x4;

static __device__ __forceinline__ unsigned short f2bf(float f) {
  union { float f; unsigned int u; } v; v.f = f;
  unsigned int r = (v.u + 0x7FFFu + ((v.u >> 16) & 1u)) >> 16;  // RNE
  return (unsigned short)r;
}

static __device__ __forceinline__ bf16x8 pack8(const float* f) {
  bf16x8 r;
#pragma unroll
  for (int i = 0; i < 8; ++i) r[i] = (short)f2bf(f[i]);
  return r;
}

// HW packed f32->bf16 (RNE): lo16 = bf16(a), hi16 = bf16(b)
static __device__ __forceinline__ unsigned cvt_pk_bf16(float a, float b) {
  unsigned r;
  asm("v_cvt_pk_bf16_f32 %0, %1, %2" : "=v"(r) : "v"(a), "v"(b));
  return r;
}

// fast 8x f32 -> bf16x8 via 4 cvt_pk (used in out_kernel only)
static __device__ __forceinline__ bf16x8 pack8f(const float* f) {
  union { bf16x8 v; unsigned u[4]; } o;
  o.u[0] = cvt_pk_bf16(f[0], f[1]);
  o.u[1] = cvt_pk_bf16(f[2], f[3]);
  o.u[2] = cvt_pk_bf16(f[4], f[5]);
  o.u[3] = cvt_pk_bf16(f[6], f[7]);
  return o.v;
}

// ---------------------------------------------------------------------------
// pre_kernel: P'[g][dir*256 + j] = -log2e * (emb[text] . W_dir[j][0:256] + b)
// written INTO the hidden output region (scan RMWs it in place).
// dir=1 rows are time-reversed (row l holds x[511-l] terms).
// (r8 verbatim — known good)
// ---------------------------------------------------------------------------
__global__ __launch_bounds__(512) void pre_kernel(
    const int* __restrict__ text, const float* __restrict__ emb,
    const float* __restrict__ W_f, const float* __restrict__ b_f,
    const float* __restrict__ W_b, const float* __restrict__ b_b,
    float* __restrict__ hidden) {
  const int blk = blockIdx.x;          // 0..511
  const int dir = blk >> 8;
  const int base = (blk & 255) * 128;  // g-row base (g = l*64 + b)
  const float* W    = dir ? W_b : W_f;
  const float* bias = dir ? b_b : b_f;
  const int tid = threadIdx.x;
  const int w = tid >> 6, ln = tid & 63, m16 = ln & 15, g4 = ln >> 4;

  __shared__ __align__(16) unsigned char xLds[16 * 512];

  // W x-part fragments: wave w owns j-range [w*32, w*32+32), K=256
  bf16x8 wfrag[2][8];
#pragma unroll
  for (int t = 0; t < 2; ++t) {
    const int j0 = w * 32 + t * 16 + m16;
#pragma unroll
    for (int kk = 0; kk < 8; ++kk) {
      const float* p = W + (long)j0 * KTOT + kk * 32 + g4 * 8;
      float4 p0 = *(const float4*)(p);
      float4 p1 = *(const float4*)(p + 4);
      float f[8] = {p0.x, p0.y, p0.z, p0.w, p1.x, p1.y, p1.z, p1.w};
      wfrag[t][kk] = pack8(f);
    }
  }
  float biasr[2][4];
#pragma unroll
  for (int t = 0; t < 2; ++t)
#pragma unroll
    for (int r = 0; r < 4; ++r) biasr[t][r] = bias[w * 32 + t * 16 + 4 * g4 + r];

  const int xm = tid >> 5;          // staged row
  const int e0 = (tid & 31) * 8;    // 8 contiguous f32 per thread

  for (int mt = 0; mt < 8; ++mt) {
    const int g = base + mt * 16 + xm;
    const int l = g >> 6, b = g & 63;
    const int srcl = dir ? (L_SEQ - 1 - l) : l;
    const int tok = text[srcl * BATCH + b];
    const float* xp = emb + (long)tok * 256 + e0;
    float4 a0 = *(const float4*)(xp);
    float4 a1 = *(const float4*)(xp + 4);
    float f[8] = {a0.x, a0.y, a0.z, a0.w, a1.x, a1.y, a1.z, a1.w};
    bf16x8 xv = pack8(f);
    if (mt) __syncthreads();  // prior tile's reads done before overwrite
    *(bf16x8*)(xLds + xm * 512 + ((e0 * 2) ^ ((xm & 7) << 4))) = xv;
    __syncthreads();

    f32x4 acc0 = {0.f, 0.f, 0.f, 0.f};
    f32x4 acc1 = {0.f, 0.f, 0.f, 0.f};
#pragma unroll
    for (int kk = 0; kk < 8; ++kk) {
      bf16x8 uf = *(const bf16x8*)(xLds + m16 * 512 +
                                   (((kk * 64) + g4 * 16) ^ ((m16 & 7) << 4)));
      acc0 = __builtin_amdgcn_mfma_f32_16x16x32_bf16(wfrag[0][kk], uf, acc0, 0, 0, 0);
      acc1 = __builtin_amdgcn_mfma_f32_16x16x32_bf16(wfrag[1][kk], uf, acc1, 0, 0, 0);
    }
    const int gg = base + mt * 16 + m16;
    float* op = hidden + (long)gg * HID2 + dir * 256 + w * 32 + 4 * g4;
    *(float4*)(op)      = make_float4(-NLOG2E * (acc0[0] + biasr[0][0]),
                                      -NLOG2E * (acc0[1] + biasr[0][1]),
                                      -NLOG2E * (acc0[2] + biasr[0][2]),
                                      -NLOG2E * (acc0[3] + biasr[0][3]));
    *(float4*)(op + 16) = make_float4(-NLOG2E * (acc1[0] + biasr[1][0]),
                                      -NLOG2E * (acc1[1] + biasr[1][1]),
                                      -NLOG2E * (acc1[2] + biasr[1][2]),
                                      -NLOG2E * (acc1[3] + biasr[1][3]));
  }
}

// ---------------------------------------------------------------------------
// scan_kernel: h' = 1/(1+exp2(P' + W'.h)), 8 WGs, 512 threads = 8 waves
// (2/SIMD), 2 j-tiles per wave, K=256.  (r8 verbatim — known good, 365 us)
// Fragment-linear LDS layout (conflict-free):
//   read  uf[kk] at  kk*1024 + ln*16            (contiguous 1KB/instr)
//   write h'(t)  at  w*1024 + (t*2+(g4>>1))*256 + m16*16 + (g4&1)*8
// P' prefetched 2 steps ahead (refill issued last), lgkmcnt-only barrier.
// ---------------------------------------------------------------------------
__global__ __launch_bounds__(512, 1) void scan_kernel(
    const float* __restrict__ W_f, const float* __restrict__ W_b,
    float* __restrict__ hidden) {
  const int wg  = blockIdx.x;     // 0..7
  const int dir = wg >> 2;
  const int b0  = (wg & 3) * 16;
  const int tid = threadIdx.x;
  const int w = tid >> 6, ln = tid & 63, m16 = ln & 15, g4 = ln >> 4;
  const float* W = dir ? W_b : W_f;

  __shared__ __align__(16) unsigned char hLds[2][8 * 1024];

  // W h-part fragments (pre-scaled by -log2e): wave w owns j in [w*32, w*32+32)
  bf16x8 wfrag[2][8];
#pragma unroll
  for (int t = 0; t < 2; ++t) {
    const int j0 = w * 32 + t * 16 + m16;
#pragma unroll
    for (int kk = 0; kk < 8; ++kk) {
      const float* p = W + (long)j0 * KTOT + 256 + kk * 32 + g4 * 8;
      float4 p0 = *(const float4*)(p);
      float4 p1 = *(const float4*)(p + 4);
      float f[8] = {-NLOG2E * p0.x, -NLOG2E * p0.y, -NLOG2E * p0.z, -NLOG2E * p0.w,
                    -NLOG2E * p1.x, -NLOG2E * p1.y, -NLOG2E * p1.z, -NLOG2E * p1.w};
      wfrag[t][kk] = pack8(f);
    }
  }

  // fragment-linear LDS offsets
  int rdoff[8];
#pragma unroll
  for (int kk = 0; kk < 8; ++kk) rdoff[kk] = kk * 1024 + ln * 16;
  const int wroff0 = w * 1024 + ((g4 >> 1) * 256) + m16 * 16 + (g4 & 1) * 8;  // t=0
  const int wroff1 = wroff0 + 512;                                            // t=1

  // zero h buffer 0 (512 threads x 16 B = 8 KB)
  *(f32x4*)(&hLds[0][0] + tid * 16) = f32x4{0.f, 0.f, 0.f, 0.f};

  // per-lane column offset into a hidden l-slice (P' read & h write alias)
  const long roff = (long)(b0 + m16) * HID2 + dir * 256 + w * 32 + 4 * g4;

  f32x4 pA0, pA1, pB0, pB1;           // P' regs: A = even steps, B = odd
  pA0 = *(const f32x4*)(hidden + roff);
  pA1 = *(const f32x4*)(hidden + roff + 16);
  pB0 = *(const f32x4*)(hidden + ROWSTRIDE + roff);
  pB1 = *(const f32x4*)(hidden + ROWSTRIDE + roff + 16);

  __syncthreads();

// one scan step: h from hLds[BUF] -> h' into hLds[BUF^1]; store row SROW;
// refill (PF0,PF1) with P'[SROW+2] at the very end (clamped at tail).
#define STEP(BUF, PF0, PF1, SROW)                                              \
  {                                                                            \
    bf16x8 uf[8];                                                              \
    _Pragma("unroll")                                                          \
    for (int kk = 0; kk < 8; ++kk)                                             \
      uf[kk] = *(const bf16x8*)(&hLds[BUF][0] + rdoff[kk]);                    \
    f32x4 acc0 = {0.f, 0.f, 0.f, 0.f};                                         \
    f32x4 acc1 = {0.f, 0.f, 0.f, 0.f};                                         \
    _Pragma("unroll")                                                          \
    for (int kk = 0; kk < 8; ++kk) {                                           \
      acc0 = __builtin_amdgcn_mfma_f32_16x16x32_bf16(wfrag[0][kk], uf[kk],     \
                                                     acc0, 0, 0, 0);           \
      acc1 = __builtin_amdgcn_mfma_f32_16x16x32_bf16(wfrag[1][kk], uf[kk],     \
                                                     acc1, 0, 0, 0);           \
    }                                                                          \
    float h0[4], h1[4];                                                        \
    _Pragma("unroll")                                                          \
    for (int r = 0; r < 4; ++r) {                                              \
      h0[r] = __builtin_amdgcn_rcpf(                                           \
          1.f + __builtin_amdgcn_exp2f(acc0[r] + PF0[r]));                     \
      h1[r] = __builtin_amdgcn_rcpf(                                           \
          1.f + __builtin_amdgcn_exp2f(acc1[r] + PF1[r]));                     \
    }                                                                          \
    *(uint2*)(&hLds[(BUF) ^ 1][0] + wroff0) =                                  \
        make_uint2(cvt_pk_bf16(h0[0], h0[1]), cvt_pk_bf16(h0[2], h0[3]));      \
    *(uint2*)(&hLds[(BUF) ^ 1][0] + wroff1) =                                  \
        make_uint2(cvt_pk_bf16(h1[0], h1[1]), cvt_pk_bf16(h1[2], h1[3]));      \
    float* gp = hidden + (long)(SROW)*ROWSTRIDE + roff;                        \
    *(float4*)(gp)      = make_float4(h0[0], h0[1], h0[2], h0[3]);             \
    *(float4*)(gp + 16) = make_float4(h1[0], h1[1], h1[2], h1[3]);             \
    {                                                                          \
      const long rn = ((SROW) + 2 < L_SEQ) ? (SROW) + 2 : L_SEQ - 1;           \
      const float* lp = hidden + rn * ROWSTRIDE + roff;                        \
      PF0 = *(const f32x4*)(lp);                                               \
      PF1 = *(const f32x4*)(lp + 16);                                          \
    }                                                                          \
    asm volatile("s_waitcnt lgkmcnt(0)" ::: "memory");                         \
    __builtin_amdgcn_s_barrier();                                              \
    asm volatile("" ::: "memory");                                             \
  }

  for (int s = 0; s < L_SEQ; s += 2) {
    STEP(0, pA0, pA1, s)
    STEP(1, pB0, pB1, s + 1)
  }
#undef STEP
}

// ---------------------------------------------------------------------------
// out[lb][t] = hidden[lb][:] . W_out[t][:] + b_out[t]
// r11: 256 blocks x 4 waves; each wave owns a PAIR of m-tiles with resident
// A fragments; W_out streamed once per nt and shared by both m-tiles.
// Same accumulation order as the r8 out_kernel -> bit-identical results.
// ---------------------------------------------------------------------------
__global__ __launch_bounds__(256, 1) void out_kernel(
    const float* __restrict__ hidden, const float* __restrict__ W_out,
    const float* __restrict__ b_out, float* __restrict__ out) {
  const int tid = threadIdx.x;
  const int w = tid >> 6, ln = tid & 63, m16 = ln & 15, g4 = ln >> 4;
  const int mtA = (blockIdx.x * 4 + w) * 2;  // pair of m-tiles per wave
  const int mtB = mtA + 1;

  bf16x8 aA[16], aB[16];
  {
    const float* hpA = hidden + (long)(mtA * 16 + m16) * HID2 + g4 * 8;
    const float* hpB = hidden + (long)(mtB * 16 + m16) * HID2 + g4 * 8;
#pragma unroll
    for (int kk = 0; kk < 16; ++kk) {
      float4 p0 = *(const float4*)(hpA + kk * 32);
      float4 p1 = *(const float4*)(hpA + kk * 32 + 4);
      float f[8] = {p0.x, p0.y, p0.z, p0.w, p1.x, p1.y, p1.z, p1.w};
      aA[kk] = pack8f(f);
      float4 q0 = *(const float4*)(hpB + kk * 32);
      float4 q1 = *(const float4*)(hpB + kk * 32 + 4);
      float g[8] = {q0.x, q0.y, q0.z, q0.w, q1.x, q1.y, q1.z, q1.w};
      aB[kk] = pack8f(g);
    }
  }

#pragma unroll
  for (int nt = 0; nt < 4; ++nt) {
    const int trow = nt * 16 + m16;
    const int rrow = trow < TDIM ? trow : 0;  // clamp: stay in-bounds
    const bool valid = trow < TDIM;
    f32x4 accA = {0.f, 0.f, 0.f, 0.f};
    f32x4 accB = {0.f, 0.f, 0.f, 0.f};
    const float* wp = W_out + (long)rrow * HID2 + g4 * 8;
#pragma unroll
    for (int kk = 0; kk < 16; ++kk) {
      float4 p0 = *(const float4*)(wp + kk * 32);
      float4 p1 = *(const float4*)(wp + kk * 32 + 4);
      float f[8] = {p0.x, p0.y, p0.z, p0.w, p1.x, p1.y, p1.z, p1.w};
      bf16x8 bf = pack8f(f);
      accA = __builtin_amdgcn_mfma_f32_16x16x32_bf16(aA[kk], bf, accA, 0, 0, 0);
      accB = __builtin_amdgcn_mfma_f32_16x16x32_bf16(aB[kk], bf, accB, 0, 0, 0);
    }
    if (valid) {
      const float bo = b_out[trow];
#pragma unroll
      for (int r = 0; r < 4; ++r) {
        out[(long)(mtA * 16 + 4 * g4 + r) * TDIM + trow] = accA[r] + bo;
        out[(long)(mtB * 16 + 4 * g4 + r) * TDIM + trow] = accB[r] + bo;
      }
    }
  }
}

extern "C" void kernel_launch(void* const* d_in, const int* in_sizes, int n_in,
                              void* d_out, int out_size, void* d_ws, size_t ws_size,
                              hipStream_t stream) {
  const int*   text  = (const int*)d_in[0];
  const float* emb   = (const float*)d_in[1];
  const float* W_f   = (const float*)d_in[2];
  const float* b_f   = (const float*)d_in[3];
  const float* W_b   = (const float*)d_in[4];
  const float* b_b   = (const float*)d_in[5];
  const float* W_out = (const float*)d_in[6];
  const float* b_out = (const float*)d_in[7];
  float* out    = (float*)d_out;
  float* hidden = out + (long)L_SEQ * BATCH * TDIM;  // second tuple output

  pre_kernel<<<512, 512, 0, stream>>>(text, emb, W_f, b_f, W_b, b_b, hidden);
  scan_kernel<<<8, 512, 0, stream>>>(W_f, W_b, hidden);
  out_kernel<<<256, 256, 0, stream>>>(hidden, W_out, b_out, out);
}

// Round 12
// 425.429 us; speedup vs baseline: 1.3043x; 1.0114x over previous
//
#include <hip/hip_runtime.h>
#include <stdint.h>

#define L_SEQ 512
#define BATCH 64
#define KTOT  512   // E + H
#define TDIM  50
#define HID2  512   // 2*H
#define ROWSTRIDE ((long)BATCH * HID2)  // floats per l-slice of hidden
#define NLOG2E 1.4426950408889634f     // P' = -log2e*(Wx+b); W' = -log2e*W_h

typedef __attribute__((ext_vector_type(8))) short bf16x8;
typedef __attribute__((ext_vector_type(4))) float f32x4;

// HW packed f32->bf16 (RNE): lo16 = bf16(a), hi16 = bf16(b)
static __device__ __forceinline__ unsigned cvt_pk_bf16(float a, float b) {
  unsigned r;
  asm("v_cvt_pk_bf16_f32 %0, %1, %2" : "=v"(r) : "v"(a), "v"(b));
  return r;
}

// 8x f32 -> bf16x8 via 4 HW cvt_pk (RNE; identical to software RNE for all
// finite values — no NaN/Inf/denormal concerns in this problem's data)
static __device__ __forceinline__ bf16x8 pack8(const float* f) {
  union { bf16x8 v; unsigned u[4]; } o;
  o.u[0] = cvt_pk_bf16(f[0], f[1]);
  o.u[1] = cvt_pk_bf16(f[2], f[3]);
  o.u[2] = cvt_pk_bf16(f[4], f[5]);
  o.u[3] = cvt_pk_bf16(f[6], f[7]);
  return o.v;
}

// ---------------------------------------------------------------------------
// pre_kernel: P'[g][dir*256 + j] = -log2e * (emb[text] . W_dir[j][0:256] + b)
// written INTO the hidden output region (scan RMWs it in place).
// dir=1 rows are time-reversed (row l holds x[511-l] terms).
// (r8 structure; pack8 now HW cvt_pk)
// ---------------------------------------------------------------------------
__global__ __launch_bounds__(512) void pre_kernel(
    const int* __restrict__ text, const float* __restrict__ emb,
    const float* __restrict__ W_f, const float* __restrict__ b_f,
    const float* __restrict__ W_b, const float* __restrict__ b_b,
    float* __restrict__ hidden) {
  const int blk = blockIdx.x;          // 0..511
  const int dir = blk >> 8;
  const int base = (blk & 255) * 128;  // g-row base (g = l*64 + b)
  const float* W    = dir ? W_b : W_f;
  const float* bias = dir ? b_b : b_f;
  const int tid = threadIdx.x;
  const int w = tid >> 6, ln = tid & 63, m16 = ln & 15, g4 = ln >> 4;

  __shared__ __align__(16) unsigned char xLds[16 * 512];

  // W x-part fragments: wave w owns j-range [w*32, w*32+32), K=256
  bf16x8 wfrag[2][8];
#pragma unroll
  for (int t = 0; t < 2; ++t) {
    const int j0 = w * 32 + t * 16 + m16;
#pragma unroll
    for (int kk = 0; kk < 8; ++kk) {
      const float* p = W + (long)j0 * KTOT + kk * 32 + g4 * 8;
      float4 p0 = *(const float4*)(p);
      float4 p1 = *(const float4*)(p + 4);
      float f[8] = {p0.x, p0.y, p0.z, p0.w, p1.x, p1.y, p1.z, p1.w};
      wfrag[t][kk] = pack8(f);
    }
  }
  float biasr[2][4];
#pragma unroll
  for (int t = 0; t < 2; ++t)
#pragma unroll
    for (int r = 0; r < 4; ++r) biasr[t][r] = bias[w * 32 + t * 16 + 4 * g4 + r];

  const int xm = tid >> 5;          // staged row
  const int e0 = (tid & 31) * 8;    // 8 contiguous f32 per thread

  for (int mt = 0; mt < 8; ++mt) {
    const int g = base + mt * 16 + xm;
    const int l = g >> 6, b = g & 63;
    const int srcl = dir ? (L_SEQ - 1 - l) : l;
    const int tok = text[srcl * BATCH + b];
    const float* xp = emb + (long)tok * 256 + e0;
    float4 a0 = *(const float4*)(xp);
    float4 a1 = *(const float4*)(xp + 4);
    float f[8] = {a0.x, a0.y, a0.z, a0.w, a1.x, a1.y, a1.z, a1.w};
    bf16x8 xv = pack8(f);
    if (mt) __syncthreads();  // prior tile's reads done before overwrite
    *(bf16x8*)(xLds + xm * 512 + ((e0 * 2) ^ ((xm & 7) << 4))) = xv;
    __syncthreads();

    f32x4 acc0 = {0.f, 0.f, 0.f, 0.f};
    f32x4 acc1 = {0.f, 0.f, 0.f, 0.f};
#pragma unroll
    for (int kk = 0; kk < 8; ++kk) {
      bf16x8 uf = *(const bf16x8*)(xLds + m16 * 512 +
                                   (((kk * 64) + g4 * 16) ^ ((m16 & 7) << 4)));
      acc0 = __builtin_amdgcn_mfma_f32_16x16x32_bf16(wfrag[0][kk], uf, acc0, 0, 0, 0);
      acc1 = __builtin_amdgcn_mfma_f32_16x16x32_bf16(wfrag[1][kk], uf, acc1, 0, 0, 0);
    }
    const int gg = base + mt * 16 + m16;
    float* op = hidden + (long)gg * HID2 + dir * 256 + w * 32 + 4 * g4;
    *(float4*)(op)      = make_float4(-NLOG2E * (acc0[0] + biasr[0][0]),
                                      -NLOG2E * (acc0[1] + biasr[0][1]),
                                      -NLOG2E * (acc0[2] + biasr[0][2]),
                                      -NLOG2E * (acc0[3] + biasr[0][3]));
    *(float4*)(op + 16) = make_float4(-NLOG2E * (acc1[0] + biasr[1][0]),
                                      -NLOG2E * (acc1[1] + biasr[1][1]),
                                      -NLOG2E * (acc1[2] + biasr[1][2]),
                                      -NLOG2E * (acc1[3] + biasr[1][3]));
  }
}

// ---------------------------------------------------------------------------
// scan_kernel: h' = 1/(1+exp2(P' + W'.h)), 8 WGs, 512 threads = 8 waves
// (2/SIMD), 2 j-tiles per wave, K=256.  (r8 structure — measured floor)
// Fragment-linear LDS layout (conflict-free):
//   read  uf[kk] at  kk*1024 + ln*16            (contiguous 1KB/instr)
//   write h'(t)  at  w*1024 + (t*2+(g4>>1))*256 + m16*16 + (g4&1)*8
// P' prefetched 2 steps ahead (refill issued last), lgkmcnt-only barrier.
// ---------------------------------------------------------------------------
__global__ __launch_bounds__(512, 1) void scan_kernel(
    const float* __restrict__ W_f, const float* __restrict__ W_b,
    float* __restrict__ hidden) {
  const int wg  = blockIdx.x;     // 0..7
  const int dir = wg >> 2;
  const int b0  = (wg & 3) * 16;
  const int tid = threadIdx.x;
  const int w = tid >> 6, ln = tid & 63, m16 = ln & 15, g4 = ln >> 4;
  const float* W = dir ? W_b : W_f;

  __shared__ __align__(16) unsigned char hLds[2][8 * 1024];

  // W h-part fragments (pre-scaled by -log2e): wave w owns j in [w*32, w*32+32)
  bf16x8 wfrag[2][8];
#pragma unroll
  for (int t = 0; t < 2; ++t) {
    const int j0 = w * 32 + t * 16 + m16;
#pragma unroll
    for (int kk = 0; kk < 8; ++kk) {
      const float* p = W + (long)j0 * KTOT + 256 + kk * 32 + g4 * 8;
      float4 p0 = *(const float4*)(p);
      float4 p1 = *(const float4*)(p + 4);
      float f[8] = {-NLOG2E * p0.x, -NLOG2E * p0.y, -NLOG2E * p0.z, -NLOG2E * p0.w,
                    -NLOG2E * p1.x, -NLOG2E * p1.y, -NLOG2E * p1.z, -NLOG2E * p1.w};
      wfrag[t][kk] = pack8(f);
    }
  }

  // fragment-linear LDS offsets
  int rdoff[8];
#pragma unroll
  for (int kk = 0; kk < 8; ++kk) rdoff[kk] = kk * 1024 + ln * 16;
  const int wroff0 = w * 1024 + ((g4 >> 1) * 256) + m16 * 16 + (g4 & 1) * 8;  // t=0
  const int wroff1 = wroff0 + 512;                                            // t=1

  // zero h buffer 0 (512 threads x 16 B = 8 KB)
  *(f32x4*)(&hLds[0][0] + tid * 16) = f32x4{0.f, 0.f, 0.f, 0.f};

  // per-lane column offset into a hidden l-slice (P' read & h write alias)
  const long roff = (long)(b0 + m16) * HID2 + dir * 256 + w * 32 + 4 * g4;

  f32x4 pA0, pA1, pB0, pB1;           // P' regs: A = even steps, B = odd
  pA0 = *(const f32x4*)(hidden + roff);
  pA1 = *(const f32x4*)(hidden + roff + 16);
  pB0 = *(const f32x4*)(hidden + ROWSTRIDE + roff);
  pB1 = *(const f32x4*)(hidden + ROWSTRIDE + roff + 16);

  __syncthreads();

// one scan step: h from hLds[BUF] -> h' into hLds[BUF^1]; store row SROW;
// refill (PF0,PF1) with P'[SROW+2] at the very end (clamped at tail).
#define STEP(BUF, PF0, PF1, SROW)                                              \
  {                                                                            \
    bf16x8 uf[8];                                                              \
    _Pragma("unroll")                                                          \
    for (int kk = 0; kk < 8; ++kk)                                             \
      uf[kk] = *(const bf16x8*)(&hLds[BUF][0] + rdoff[kk]);                    \
    f32x4 acc0 = {0.f, 0.f, 0.f, 0.f};                                         \
    f32x4 acc1 = {0.f, 0.f, 0.f, 0.f};                                         \
    _Pragma("unroll")                                                          \
    for (int kk = 0; kk < 8; ++kk) {                                           \
      acc0 = __builtin_amdgcn_mfma_f32_16x16x32_bf16(wfrag[0][kk], uf[kk],     \
                                                     acc0, 0, 0, 0);           \
      acc1 = __builtin_amdgcn_mfma_f32_16x16x32_bf16(wfrag[1][kk], uf[kk],     \
                                                     acc1, 0, 0, 0);           \
    }                                                                          \
    float h0[4], h1[4];                                                        \
    _Pragma("unroll")                                                          \
    for (int r = 0; r < 4; ++r) {                                              \
      h0[r] = __builtin_amdgcn_rcpf(                                           \
          1.f + __builtin_amdgcn_exp2f(acc0[r] + PF0[r]));                     \
      h1[r] = __builtin_amdgcn_rcpf(                                           \
          1.f + __builtin_amdgcn_exp2f(acc1[r] + PF1[r]));                     \
    }                                                                          \
    *(uint2*)(&hLds[(BUF) ^ 1][0] + wroff0) =                                  \
        make_uint2(cvt_pk_bf16(h0[0], h0[1]), cvt_pk_bf16(h0[2], h0[3]));      \
    *(uint2*)(&hLds[(BUF) ^ 1][0] + wroff1) =                                  \
        make_uint2(cvt_pk_bf16(h1[0], h1[1]), cvt_pk_bf16(h1[2], h1[3]));      \
    float* gp = hidden + (long)(SROW)*ROWSTRIDE + roff;                        \
    *(float4*)(gp)      = make_float4(h0[0], h0[1], h0[2], h0[3]);             \
    *(float4*)(gp + 16) = make_float4(h1[0], h1[1], h1[2], h1[3]);             \
    {                                                                          \
      const long rn = ((SROW) + 2 < L_SEQ) ? (SROW) + 2 : L_SEQ - 1;           \
      const float* lp = hidden + rn * ROWSTRIDE + roff;                        \
      PF0 = *(const f32x4*)(lp);                                               \
      PF1 = *(const f32x4*)(lp + 16);                                          \
    }                                                                          \
    asm volatile("s_waitcnt lgkmcnt(0)" ::: "memory");                         \
    __builtin_amdgcn_s_barrier();                                              \
    asm volatile("" ::: "memory");                                             \
  }

  for (int s = 0; s < L_SEQ; s += 2) {
    STEP(0, pA0, pA1, s)
    STEP(1, pB0, pB1, s + 1)
  }
#undef STEP
}

// ---------------------------------------------------------------------------
// out[lb][t] = hidden[lb][:] . W_out[t][:] + b_out[t]
// 256 blocks x 4 waves; each wave owns a PAIR of m-tiles with resident
// A fragments; W_out streamed once per nt and shared by both m-tiles.
// ---------------------------------------------------------------------------
__global__ __launch_bounds__(256, 1) void out_kernel(
    const float* __restrict__ hidden, const float* __restrict__ W_out,
    const float* __restrict__ b_out, float* __restrict__ out) {
  const int tid = threadIdx.x;
  const int w = tid >> 6, ln = tid & 63, m16 = ln & 15, g4 = ln >> 4;
  const int mtA = (blockIdx.x * 4 + w) * 2;  // pair of m-tiles per wave
  const int mtB = mtA + 1;

  bf16x8 aA[16], aB[16];
  {
    const float* hpA = hidden + (long)(mtA * 16 + m16) * HID2 + g4 * 8;
    const float* hpB = hidden + (long)(mtB * 16 + m16) * HID2 + g4 * 8;
#pragma unroll
    for (int kk = 0; kk < 16; ++kk) {
      float4 p0 = *(const float4*)(hpA + kk * 32);
      float4 p1 = *(const float4*)(hpA + kk * 32 + 4);
      float f[8] = {p0.x, p0.y, p0.z, p0.w, p1.x, p1.y, p1.z, p1.w};
      aA[kk] = pack8(f);
      float4 q0 = *(const float4*)(hpB + kk * 32);
      float4 q1 = *(const float4*)(hpB + kk * 32 + 4);
      float g[8] = {q0.x, q0.y, q0.z, q0.w, q1.x, q1.y, q1.z, q1.w};
      aB[kk] = pack8(g);
    }
  }

#pragma unroll
  for (int nt = 0; nt < 4; ++nt) {
    const int trow = nt * 16 + m16;
    const int rrow = trow < TDIM ? trow : 0;  // clamp: stay in-bounds
    const bool valid = trow < TDIM;
    f32x4 accA = {0.f, 0.f, 0.f, 0.f};
    f32x4 accB = {0.f, 0.f, 0.f, 0.f};
    const float* wp = W_out + (long)rrow * HID2 + g4 * 8;
#pragma unroll
    for (int kk = 0; kk < 16; ++kk) {
      float4 p0 = *(const float4*)(wp + kk * 32);
      float4 p1 = *(const float4*)(wp + kk * 32 + 4);
      float f[8] = {p0.x, p0.y, p0.z, p0.w, p1.x, p1.y, p1.z, p1.w};
      bf16x8 bf = pack8(f);
      accA = __builtin_amdgcn_mfma_f32_16x16x32_bf16(aA[kk], bf, accA, 0, 0, 0);
      accB = __builtin_amdgcn_mfma_f32_16x16x32_bf16(aB[kk], bf, accB, 0, 0, 0);
    }
    if (valid) {
      const float bo = b_out[trow];
#pragma unroll
      for (int r = 0; r < 4; ++r) {
        out[(long)(mtA * 16 + 4 * g4 + r) * TDIM + trow] = accA[r] + bo;
        out[(long)(mtB * 16 + 4 * g4 + r) * TDIM + trow] = accB[r] + bo;
      }
    }
  }
}

extern "C" void kernel_launch(void* const* d_in, const int* in_sizes, int n_in,
                              void* d_out, int out_size, void* d_ws, size_t ws_size,
                              hipStream_t stream) {
  const int*   text  = (const int*)d_in[0];
  const float* emb   = (const float*)d_in[1];
  const float* W_f   = (const float*)d_in[2];
  const float* b_f   = (const float*)d_in[3];
  const float* W_b   = (const float*)d_in[4];
  const float* b_b   = (const float*)d_in[5];
  const float* W_out = (const float*)d_in[6];
  const float* b_out = (const float*)d_in[7];
  float* out    = (float*)d_out;
  float* hidden = out + (long)L_SEQ * BATCH * TDIM;  // second tuple output

  pre_kernel<<<512, 512, 0, stream>>>(text, emb, W_f, b_f, W_b, b_b, hidden);
  scan_kernel<<<8, 512, 0, stream>>>(W_f, W_b, hidden);
  out_kernel<<<256, 256, 0, stream>>>(hidden, W_out, b_out, out);
}